// Round 4
// baseline (831.829 us; speedup 1.0000x reference)
//
#include <hip/hip_runtime.h>
#include <hip/hip_bf16.h>

typedef __bf16 bf16_t;
typedef __bf16 bf16x8 __attribute__((ext_vector_type(8)));
typedef __bf16 bf16x4 __attribute__((ext_vector_type(4)));
typedef __bf16 bf16x2 __attribute__((ext_vector_type(2)));
typedef float f32x4 __attribute__((ext_vector_type(4)));

typedef const __attribute__((address_space(1))) void* gas_t;
typedef __attribute__((address_space(3))) void* las_t;

constexpr int Hh = 56;
constexpr int Ww = 56;
constexpr int Cc = 512;
constexpr int NHd = 16;
constexpr int HD = 32;
constexpr int SSh = 3;
constexpr int Nn = 49;          // tokens per window
constexpr long Mtot = 100352;   // 32*64*49 windowed tokens
#define SCALE 0.17677669529663687f

// token (windowed order) -> pixel index in x / out. Identical map for gather and scatter.
__device__ __forceinline__ int token_to_pixel(int m) {
  int bw = m / Nn;
  int n  = m - bw * Nn;
  int b  = bw >> 6;
  int w6 = bw & 63;
  int wh = w6 >> 3, ww = w6 & 7;
  int r = n / 7, c = n - r * 7;
  int hh = wh * 7 + r + SSh; if (hh >= Hh) hh -= Hh;
  int wp = ww * 7 + c + SSh; if (wp >= Ww) wp -= Ww;
  return (b * Hh + hh) * Ww + wp;
}

// Gather+convert: x (f32 pixels) -> xb (bf16, windowed token-major), and qkv_w -> bf16.
__global__ __launch_bounds__(256)
void prep_k(const float* __restrict__ x, const float* __restrict__ qkv_w,
            bf16_t* __restrict__ xb, bf16_t* __restrict__ qwb) {
  const int b = blockIdx.x, t = threadIdx.x;
  if (b < (int)(Mtot / 4)) {
    const int m = b * 4 + (t >> 6);
    const int lane = t & 63;
    const float* src = x + (long)token_to_pixel(m) * Cc + lane * 8;
    f32x4 a0 = *(const f32x4*)src;
    f32x4 a1 = *(const f32x4*)(src + 4);
    bf16x8 o;
#pragma unroll
    for (int e = 0; e < 4; ++e) { o[e] = (bf16_t)a0[e]; o[e + 4] = (bf16_t)a1[e]; }
    *(bf16x8*)(xb + (long)m * Cc + lane * 8) = o;
  } else {
    const long off = (long)(b - Mtot / 4) * 2048 + t * 8;
    f32x4 a0 = *(const f32x4*)(qkv_w + off);
    f32x4 a1 = *(const f32x4*)(qkv_w + off + 4);
    bf16x8 o;
#pragma unroll
    for (int e = 0; e < 4; ++e) { o[e] = (bf16_t)a0[e]; o[e + 4] = (bf16_t)a1[e]; }
    *(bf16x8*)(qwb + off) = o;
  }
}

// proj_w f32 -> bf16 (into the dead kr region)
__global__ __launch_bounds__(256)
void convp_k(const float* __restrict__ w, bf16_t* __restrict__ wb) {
  const long off = (long)blockIdx.x * 2048 + threadIdx.x * 8;
  f32x4 a0 = *(const f32x4*)(w + off);
  f32x4 a1 = *(const f32x4*)(w + off + 4);
  bf16x8 o;
#pragma unroll
  for (int e = 0; e < 4; ++e) { o[e] = (bf16_t)a0[e]; o[e + 4] = (bf16_t)a1[e]; }
  *(bf16x8*)(wb + off) = o;
}

// C[m][n] = sum_k A[m][k]*Wb[n][k] (+bias). BK=32, DOUBLE-BUFFERED LDS with
// prefetch-before-compute (T3 minimum 2-phase: stage(t+1) -> compute(t) -> barrier,
// so the barrier's vmcnt(0) drain lands after the MFMAs, hiding HBM latency).
// XOR-swizzled LDS (rule #21: linear dest + inverse-swizzled global source + swizzled
// ds_read; chunk ^= row&3 -> 2-way conflicts = free).
// XCD-chunked block swizzle (T1): each XCD gets a contiguous mtile-major run so the
// A-tile is L2-resident across its NT sibling ntile blocks.
// MODE 0: A = xb (token-major), Wb = qkv_wb; scatter bf16 q/k/v into (bw,h,n,d); q pre-scaled.
// MODE 1: A = attn_out in (bw,h,n,d), Wb = proj_wb; scatter f32 to rolled pixel layout.
template <int MODE>
__global__ __launch_bounds__(256, 4)
void gemm_k(const bf16_t* __restrict__ A, const bf16_t* __restrict__ Wb,
            const float* __restrict__ bias,
            bf16_t* __restrict__ oq, bf16_t* __restrict__ okk, bf16_t* __restrict__ ov,
            float* __restrict__ of) {
  __shared__ __align__(16) bf16_t lA[2 * 128 * 32];
  __shared__ __align__(16) bf16_t lB[2 * 128 * 32];
  constexpr int NT = (MODE == 0) ? 12 : 4;       // ntiles
  constexpr int PER = (MODE == 0) ? 1176 : 392;  // nwg/8 (both divisible by 8)
  const int t = threadIdx.x;
  const int hflat = blockIdx.y * NT + blockIdx.x;
  const int l = (hflat & 7) * PER + (hflat >> 3); // XCD-chunked, bijective
  const int mtile = l / NT, ntile = l % NT;
  const int lane = t & 63;
  const int wave = t >> 6;
  const int wr = wave >> 1, wc = wave & 1;
  const int quad = lane >> 4, l15 = lane & 15;

  // staging round p: row r = 64p + (t>>2), chunk slot (t&3).
  // Slot (r,s) holds logical chunk s^(r&3)  =>  fetch csw = (t&3)^(r&3).
  const int rr = t >> 2;
  const int csw = (t & 3) ^ (rr & 3);
  const bf16_t* aSrc[2];
  const bf16_t* bSrc[2];
  const long aStep = (MODE == 0) ? 32 : (long)Nn * HD;  // elements per 32-k slab
#pragma unroll
  for (int p = 0; p < 2; ++p) {
    const int r = 64 * p + rr;
    const int m = mtile * 128 + r;
    if (MODE == 0) {
      aSrc[p] = A + (long)m * Cc + csw * 8;
    } else {
      // element (m,k): k = it*32 + csw*8 + e; head = it, d = csw*8 + e
      int bw2 = m / Nn, nn = m - bw2 * Nn;
      aSrc[p] = A + (long)bw2 * (NHd * Nn * HD) + nn * HD + csw * 8;
    }
    bSrc[p] = Wb + (long)(ntile * 128 + r) * Cc + csw * 8;
  }
  // wave-uniform LDS bases (linear dest: slot index == t, 16B per lane)
  char* lAw = (char*)lA + wave * 1024;
  char* lBw = (char*)lB + wave * 1024;

  const int xsw = l15 & 3;   // row&3 for fragment rows (row = 16*x + l15)
  f32x4 acc[4][4] = {};

  auto stage = [&](int b) {
#pragma unroll
    for (int p = 0; p < 2; ++p) {
      __builtin_amdgcn_global_load_lds((gas_t)aSrc[p], (las_t)(lAw + b * 8192 + p * 4096), 16, 0, 0);
      __builtin_amdgcn_global_load_lds((gas_t)bSrc[p], (las_t)(lBw + b * 8192 + p * 4096), 16, 0, 0);
      aSrc[p] += aStep;
      bSrc[p] += 32;
    }
  };
  auto compute = [&](int b) {
    const bf16_t* Ab = lA + b * 4096;
    const bf16_t* Bb = lB + b * 4096;
    bf16x8 af[4], bfr[4];
#pragma unroll
    for (int i = 0; i < 4; ++i)
      af[i] = *(const bf16x8*)(Ab + (wr * 64 + i * 16 + l15) * 32 + ((quad ^ xsw) * 8));
#pragma unroll
    for (int j = 0; j < 4; ++j)
      bfr[j] = *(const bf16x8*)(Bb + (wc * 64 + j * 16 + l15) * 32 + ((quad ^ xsw) * 8));
#pragma unroll
    for (int i = 0; i < 4; ++i)
#pragma unroll
      for (int j = 0; j < 4; ++j)
        acc[i][j] = __builtin_amdgcn_mfma_f32_16x16x32_bf16(af[i], bfr[j], acc[i][j], 0, 0, 0);
  };

  // 16 K-iterations, double-buffered: 1 barrier per iteration.
  stage(0);
  __syncthreads();                 // buf0 staged (vmcnt drained at barrier)
#pragma unroll 1
  for (int it2 = 0; it2 < 7; ++it2) {
    stage(1); compute(0); __syncthreads();
    stage(0); compute(1); __syncthreads();
  }
  stage(1); compute(0); __syncthreads();
  compute(1);

#pragma unroll
  for (int i = 0; i < 4; ++i) {
#pragma unroll
    for (int rg = 0; rg < 4; ++rg) {
      int m = mtile * 128 + wr * 64 + i * 16 + quad * 4 + rg;
      if (MODE == 0) {
        int bw = m / Nn, n = m - bw * Nn;
#pragma unroll
        for (int j = 0; j < 4; ++j) {
          int jg = ntile * 128 + wc * 64 + j * 16 + l15;
          float v = acc[i][j][rg] + bias[jg];
          int which = jg >> 9;
          if (which == 0) v *= SCALE;   // fold softmax scale into q
          int h = (jg >> 5) & 15;
          int d = jg & 31;
          long idx = (((long)bw * NHd + h) * Nn + n) * HD + d;
          bf16_t* dst = (which == 0) ? oq : ((which == 1) ? okk : ov);
          dst[idx] = (bf16_t)v;
        }
      } else {
        long pb = (long)token_to_pixel(m) * Cc;
#pragma unroll
        for (int j = 0; j < 4; ++j) {
          int jg = ntile * 128 + wc * 64 + j * 16 + l15;
          of[pb + jg] = acc[i][j][rg] + bias[jg];
        }
      }
    }
  }
}

// Precompute bm[class][h][n][m] = rel-pos bias + shift mask, bf16, [64][64] padded
// with -1e30 for n>=49 or m>=49 (=> exp -> 0, so MFMA padding lanes self-mask).
__global__ void bm_fill(const float* __restrict__ table, bf16_t* __restrict__ bm) {
  const int b = blockIdx.x;           // cls*16 + h
  const int cls = b >> 4, h = b & 15;
  const int whE = cls >> 1, wwE = cls & 1;
  for (int e = threadIdx.x; e < 4096; e += 256) {
    int n = e >> 6, m = e & 63;
    float v = -1e30f;
    if (n < Nn && m < Nn) {
      int r1 = n / 7, c1 = n - r1 * 7;
      int r2 = m / 7, c2 = m - r2 * 7;
      int idx = (r1 - r2 + 6) * 13 + (c1 - c2 + 6);
      v = table[idx * NHd + h];
      int reg1 = (whE ? ((r1 < 4) ? 1 : 2) : 0) * 3 + (wwE ? ((c1 < 4) ? 1 : 2) : 0);
      int reg2 = (whE ? ((r2 < 4) ? 1 : 2) : 0) * 3 + (wwE ? ((c2 < 4) ? 1 : 2) : 0);
      if (reg1 != reg2) v -= 100.f;
    }
    bm[(long)b * 4096 + e] = (bf16_t)v;
  }
}

// MFMA attention. One block per window, 4 waves x 4 heads serial, no __syncthreads
// (all LDS per-wave; same-wave DS ops are ordered). pbuf is HALF-sized [32][72]:
// P is double-pumped (write j-pair -> read -> overwrite) since acc2[dt][nt] is
// independent per nt. LDS 36.9KB/block -> 4 blocks/CU.
__global__ __launch_bounds__(256, 4)
void attn_k(bf16_t* __restrict__ qr, const bf16_t* __restrict__ kr,
            const bf16_t* __restrict__ vr, const bf16_t* __restrict__ bm) {
  __shared__ __align__(16) bf16_t vt[4][32 * 72];   // V^T per wave: [d][m], stride 72
  __shared__ __align__(16) bf16_t pbuf[4][32 * 72]; // P half-tile per wave: [n%32][m]
  const int t = threadIdx.x, wave = t >> 6, lane = t & 63;
  const int quad = lane >> 4, l15 = lane & 15;
  const int bw = blockIdx.x;
  const int w6 = bw & 63, wh = w6 >> 3, ww = w6 & 7;
  const int cls = ((wh == 7) ? 2 : 0) | ((ww == 7) ? 1 : 0);
  bf16_t* vtw = vt[wave];
  bf16_t* pw  = pbuf[wave];

  // zero vt once: cols 50..63 stay zero forever (m-padding for PV)
  {
    bf16x8 z = {};
    for (int c = lane; c < 288; c += 64) *(bf16x8*)(vtw + c * 8) = z;
  }

  const int dc = lane & 3;        // d-chunk of 8 for V transpose staging
  const int mp = lane >> 2;       // m-pair index
  const int m2 = 32 + 2 * mp;
  const int ma = (m2 > 48) ? 48 : m2;
  const int mb = (m2 + 1 > 48) ? 48 : m2 + 1;

#pragma unroll 1
  for (int hi = 0; hi < 4; ++hi) {
    const int h = wave * 4 + hi;
    const long base = (long)(bw * NHd + h) * (Nn * HD);
    const bf16_t* K = kr + base;
    const bf16_t* Q = qr + base;
    const bf16_t* V = vr + base;

    // K/Q fragments straight from global: 16 consecutive rows x 64B = coalesced 1KB/instr.
    // Rows 49..63 over-read into the next head slab: finite garbage, masked by bm pad.
    bf16x8 kf[4], qf[4];
#pragma unroll
    for (int i = 0; i < 4; ++i) {
      kf[i] = *(const bf16x8*)(K + (i * 16 + l15) * HD + quad * 8);
      qf[i] = *(const bf16x8*)(Q + (i * 16 + l15) * HD + quad * 8);
    }
    // V staging loads (issued early; LDS transpose-writes happen after the MFMAs)
    bf16x8 v0a = *(const bf16x8*)(V + (2 * mp) * HD + dc * 8);
    bf16x8 v0b = *(const bf16x8*)(V + (2 * mp + 1) * HD + dc * 8);
    bf16x8 v1a = *(const bf16x8*)(V + ma * HD + dc * 8);
    bf16x8 v1b = *(const bf16x8*)(V + mb * HD + dc * 8);

    // S^T[m][n] = sum_d K[m][d] * Qs[n][d]
    f32x4 acc[4][4];
#pragma unroll
    for (int i = 0; i < 4; ++i)
#pragma unroll
      for (int j = 0; j < 4; ++j) {
        f32x4 z = {};
        acc[i][j] = z;
      }
#pragma unroll
    for (int i = 0; i < 4; ++i)
#pragma unroll
      for (int j = 0; j < 4; ++j)
        acc[i][j] = __builtin_amdgcn_mfma_f32_16x16x32_bf16(kf[i], qf[j], acc[i][j], 0, 0, 0);

    // V^T into LDS: vt[d][m], packed bf16x2 writes (pairs of m)
#pragma unroll
    for (int e = 0; e < 8; ++e) {
      int d = dc * 8 + e;
      bf16x2 w0; w0[0] = v0a[e]; w0[1] = v0b[e];
      *(bf16x2*)(vtw + d * 72 + 2 * mp) = w0;
      if (mp <= 8) {
        bf16x2 w1; w1[0] = v1a[e]; w1[1] = (mp < 8) ? v1b[e] : (bf16_t)0.0f;
        *(bf16x2*)(vtw + d * 72 + ma) = w1;
      }
    }

    // bias+mask+pad, exp, row-sums
    const bf16_t* bmh = bm + ((long)(cls * NHd + h) << 12);
    float psum[4] = {0.f, 0.f, 0.f, 0.f};
#pragma unroll
    for (int j = 0; j < 4; ++j) {
      const int n = j * 16 + l15;
#pragma unroll
      for (int i = 0; i < 4; ++i) {
        bf16x4 bmv = *(const bf16x4*)(bmh + n * 64 + i * 16 + quad * 4);
        f32x4 e;
#pragma unroll
        for (int rg = 0; rg < 4; ++rg)
          e[rg] = __expf(acc[i][j][rg] + (float)bmv[rg]);
        acc[i][j] = e;
        psum[j] += e[0] + e[1] + e[2] + e[3];
      }
    }
    float inv[4];
#pragma unroll
    for (int j = 0; j < 4; ++j) {
      float s = psum[j];
      s += __shfl_xor(s, 16);
      s += __shfl_xor(s, 32);
      inv[j] = (s > 0.f) ? (1.f / s) : 0.f;   // padded queries: sum==0 -> P=0, no NaN
    }

    // hoist V fragments (vt writes above are same-wave ordered before these reads)
    bf16x8 vf[2][2];
#pragma unroll
    for (int mk = 0; mk < 2; ++mk)
#pragma unroll
      for (int dt = 0; dt < 2; ++dt)
        vf[mk][dt] = *(const bf16x8*)(vtw + (dt * 16 + l15) * 72 + mk * 32 + quad * 8);

    // O^T[d][n] = sum_m VT[d][m] * P[n][m], double-pumped through half-size pbuf
    f32x4 acc2[2][4];
#pragma unroll
    for (int dt = 0; dt < 2; ++dt)
#pragma unroll
      for (int nt = 0; nt < 4; ++nt) {
        f32x4 z = {};
        acc2[dt][nt] = z;
      }
#pragma unroll
    for (int jh = 0; jh < 2; ++jh) {
#pragma unroll
      for (int jl = 0; jl < 2; ++jl) {
        const int j = jh * 2 + jl;
#pragma unroll
        for (int i = 0; i < 4; ++i) {
          bf16x4 pv;
#pragma unroll
          for (int rg = 0; rg < 4; ++rg) pv[rg] = (bf16_t)(acc[i][j][rg] * inv[j]);
          *(bf16x4*)(pw + (jl * 16 + l15) * 72 + i * 16 + quad * 4) = pv;
        }
      }
#pragma unroll
      for (int mk = 0; mk < 2; ++mk) {
        bf16x8 pf[2];
#pragma unroll
        for (int jl = 0; jl < 2; ++jl)
          pf[jl] = *(const bf16x8*)(pw + (jl * 16 + l15) * 72 + mk * 32 + quad * 8);
#pragma unroll
        for (int dt = 0; dt < 2; ++dt)
#pragma unroll
          for (int jl = 0; jl < 2; ++jl)
            acc2[dt][jh * 2 + jl] =
                __builtin_amdgcn_mfma_f32_16x16x32_bf16(vf[mk][dt], pf[jl], acc2[dt][jh * 2 + jl], 0, 0, 0);
      }
    }

    // store O[n][d] back over the q slab (this head's Q already consumed)
    bf16_t* O = qr + base;
#pragma unroll
    for (int nt = 0; nt < 4; ++nt) {
      int n = nt * 16 + l15;
      if (n < Nn) {
#pragma unroll
        for (int dt = 0; dt < 2; ++dt) {
          bf16x4 ov;
#pragma unroll
          for (int rg = 0; rg < 4; ++rg) ov[rg] = (bf16_t)acc2[dt][nt][rg];
          *(bf16x4*)(O + n * HD + dt * 16 + quad * 4) = ov;
        }
      }
    }
  }
}

extern "C" void kernel_launch(void* const* d_in, const int* in_sizes, int n_in,
                              void* d_out, int out_size, void* d_ws, size_t ws_size,
                              hipStream_t stream) {
  const float* x      = (const float*)d_in[0];
  const float* qkv_w  = (const float*)d_in[1];
  const float* qkv_b  = (const float*)d_in[2];
  const float* proj_w = (const float*)d_in[3];
  const float* proj_b = (const float*)d_in[4];
  const float* table  = (const float*)d_in[5];
  float* out = (float*)d_out;

  bf16_t* qr = (bf16_t*)d_ws;                 // q, later overwritten with attn_out
  bf16_t* kr = qr + Mtot * Cc;
  bf16_t* vr = kr + Mtot * Cc;

  // d_out doubles as scratch for everything consumed before gemm_k<1> runs:
  //   xb  @ 0        : 102,760,448 B (bf16 gathered x)
  //   bm  @ 102.76MB :     524,288 B (bias+mask table)
  //   qwb @ +512KB   :   1,572,864 B (bf16 qkv weights)
  char* ob = (char*)d_out;
  bf16_t* xb  = (bf16_t*)ob;
  bf16_t* bmb = (bf16_t*)(ob + 102760448);
  bf16_t* qwb = (bf16_t*)(ob + 102760448 + 524288);
  bf16_t* pwb = kr;   // proj_w bf16 into kr (dead after attn_k)

  prep_k<<<dim3(Mtot / 4 + 384), dim3(256), 0, stream>>>(x, qkv_w, xb, qwb);
  bm_fill<<<dim3(64), dim3(256), 0, stream>>>(table, bmb);
  dim3 g1(12, 784);   // ntile fast; XCD-chunked swizzle inside the kernel
  gemm_k<0><<<g1, 256, 0, stream>>>(xb, qwb, qkv_b, qr, kr, vr, nullptr);
  attn_k<<<dim3(2048), dim3(256), 0, stream>>>(qr, kr, vr, bmb);
  convp_k<<<dim3(128), dim3(256), 0, stream>>>(proj_w, pwb);
  dim3 g3(4, 784);
  gemm_k<1><<<g3, 256, 0, stream>>>(qr, pwb, proj_b, nullptr, nullptr, nullptr, out);
}

// Round 5
// 815.283 us; speedup vs baseline: 1.0203x; 1.0203x over previous
//
#include <hip/hip_runtime.h>
#include <hip/hip_bf16.h>

typedef __bf16 bf16_t;
typedef __bf16 bf16x8 __attribute__((ext_vector_type(8)));
typedef __bf16 bf16x4 __attribute__((ext_vector_type(4)));
typedef __bf16 bf16x2 __attribute__((ext_vector_type(2)));
typedef float f32x4 __attribute__((ext_vector_type(4)));

typedef const __attribute__((address_space(1))) void* gas_t;
typedef __attribute__((address_space(3))) void* las_t;

constexpr int Hh = 56;
constexpr int Ww = 56;
constexpr int Cc = 512;
constexpr int NHd = 16;
constexpr int HD = 32;
constexpr int SSh = 3;
constexpr int Nn = 49;          // tokens per window
constexpr long Mtot = 100352;   // 32*64*49 windowed tokens
#define SCALE 0.17677669529663687f

// token (windowed order) -> pixel index in x / out. Identical map for gather and scatter.
__device__ __forceinline__ int token_to_pixel(int m) {
  int bw = m / Nn;
  int n  = m - bw * Nn;
  int b  = bw >> 6;
  int w6 = bw & 63;
  int wh = w6 >> 3, ww = w6 & 7;
  int r = n / 7, c = n - r * 7;
  int hh = wh * 7 + r + SSh; if (hh >= Hh) hh -= Hh;
  int wp = ww * 7 + c + SSh; if (wp >= Ww) wp -= Ww;
  return (b * Hh + hh) * Ww + wp;
}

// Gather+convert: x (f32 pixels) -> xb (bf16, windowed token-major), and qkv_w -> bf16.
__global__ __launch_bounds__(256)
void prep_k(const float* __restrict__ x, const float* __restrict__ qkv_w,
            bf16_t* __restrict__ xb, bf16_t* __restrict__ qwb) {
  const int b = blockIdx.x, t = threadIdx.x;
  if (b < (int)(Mtot / 4)) {
    const int m = b * 4 + (t >> 6);
    const int lane = t & 63;
    const float* src = x + (long)token_to_pixel(m) * Cc + lane * 8;
    f32x4 a0 = *(const f32x4*)src;
    f32x4 a1 = *(const f32x4*)(src + 4);
    bf16x8 o;
#pragma unroll
    for (int e = 0; e < 4; ++e) { o[e] = (bf16_t)a0[e]; o[e + 4] = (bf16_t)a1[e]; }
    *(bf16x8*)(xb + (long)m * Cc + lane * 8) = o;
  } else {
    const long off = (long)(b - Mtot / 4) * 2048 + t * 8;
    f32x4 a0 = *(const f32x4*)(qkv_w + off);
    f32x4 a1 = *(const f32x4*)(qkv_w + off + 4);
    bf16x8 o;
#pragma unroll
    for (int e = 0; e < 4; ++e) { o[e] = (bf16_t)a0[e]; o[e + 4] = (bf16_t)a1[e]; }
    *(bf16x8*)(qwb + off) = o;
  }
}

// proj_w f32 -> bf16 (into the dead kr region)
__global__ __launch_bounds__(256)
void convp_k(const float* __restrict__ w, bf16_t* __restrict__ wb) {
  const long off = (long)blockIdx.x * 2048 + threadIdx.x * 8;
  f32x4 a0 = *(const f32x4*)(w + off);
  f32x4 a1 = *(const f32x4*)(w + off + 4);
  bf16x8 o;
#pragma unroll
  for (int e = 0; e < 4; ++e) { o[e] = (bf16_t)a0[e]; o[e + 4] = (bf16_t)a1[e]; }
  *(bf16x8*)(wb + off) = o;
}

// C[m][n] = sum_k A[m][k]*Wb[n][k] (+bias). BK=32, 3-buffer pipeline with COUNTED
// vmcnt (T3+T4): raw s_barrier (no vmcnt(0) drain) + s_waitcnt vmcnt(4) waits only
// for stage(t), leaving stage(t+1)'s 4 loads in flight across the barrier.
// stage(t+2) is issued AFTER the barrier (all waves passed compute(t-1) -> its
// buffer is free). T5 setprio around the MFMA cluster (schedule has role-split).
// LDS swizzle: bank_start = 16*(row&1)+4*chunk  =>  chunk ^= (row>>1)&3 covers all
// 8 (parity,chunk) combos with 2 lanes each = conflict-free (round-4 bug: row&3
// picked same-parity lanes -> 8-way, the 19.3M counter).
// XCD-chunked block swizzle (T1): contiguous mtile-major run per XCD, A L2-resident.
template <int MODE>
__global__ __launch_bounds__(256, 3)
void gemm_k(const bf16_t* __restrict__ A, const bf16_t* __restrict__ Wb,
            const float* __restrict__ bias,
            bf16_t* __restrict__ oq, bf16_t* __restrict__ okk, bf16_t* __restrict__ ov,
            float* __restrict__ of) {
  __shared__ __align__(16) bf16_t lA[3 * 128 * 32];
  __shared__ __align__(16) bf16_t lB[3 * 128 * 32];
  constexpr int NT = (MODE == 0) ? 12 : 4;       // ntiles
  constexpr int PER = (MODE == 0) ? 1176 : 392;  // nwg/8 (both divisible by 8)
  const int t = threadIdx.x;
  const int hflat = blockIdx.y * NT + blockIdx.x;
  const int l = (hflat & 7) * PER + (hflat >> 3); // XCD-chunked, bijective
  const int mtile = l / NT, ntile = l % NT;
  const int lane = t & 63;
  const int wave = t >> 6;
  const int wr = wave >> 1, wc = wave & 1;
  const int quad = lane >> 4, l15 = lane & 15;

  // staging round p: row r = 64p + (t>>2), chunk slot (t&3).
  // Slot (r,s) holds logical chunk s ^ ((r>>1)&3)  =>  fetch csw = (t&3)^((t>>3)&3).
  const int csw = (t & 3) ^ ((t >> 3) & 3);
  const bf16_t* aSrc[2];
  const bf16_t* bSrc[2];
  const long aStep = (MODE == 0) ? 32 : (long)Nn * HD;  // elements per 32-k slab
#pragma unroll
  for (int p = 0; p < 2; ++p) {
    const int r = 64 * p + (t >> 2);
    const int m = mtile * 128 + r;
    if (MODE == 0) {
      aSrc[p] = A + (long)m * Cc + csw * 8;
    } else {
      // element (m,k): k = it*32 + csw*8 + e; head = it, d = csw*8 + e
      int bw2 = m / Nn, nn = m - bw2 * Nn;
      aSrc[p] = A + (long)bw2 * (NHd * Nn * HD) + nn * HD + csw * 8;
    }
    bSrc[p] = Wb + (long)(ntile * 128 + r) * Cc + csw * 8;
  }
  // wave-uniform LDS byte bases (linear dest: +lane*16 per lane)
  char* lAw = (char*)lA + wave * 1024;
  char* lBw = (char*)lB + wave * 1024;

  const int fsw = (l15 >> 1) & 3;   // (row>>1)&3 for fragment rows (row = 16x + l15)
  f32x4 acc[4][4] = {};

  auto stage = [&](int b) {
#pragma unroll
    for (int p = 0; p < 2; ++p) {
      __builtin_amdgcn_global_load_lds((gas_t)aSrc[p], (las_t)(lAw + b * 8192 + p * 4096), 16, 0, 0);
      __builtin_amdgcn_global_load_lds((gas_t)bSrc[p], (las_t)(lBw + b * 8192 + p * 4096), 16, 0, 0);
      aSrc[p] += aStep;
      bSrc[p] += 32;
    }
  };
  auto compute = [&](int b) {
    const bf16_t* Ab = lA + b * 4096;
    const bf16_t* Bb = lB + b * 4096;
    bf16x8 af[4], bfr[4];
#pragma unroll
    for (int i = 0; i < 4; ++i)
      af[i] = *(const bf16x8*)(Ab + (wr * 64 + i * 16 + l15) * 32 + ((quad ^ fsw) * 8));
#pragma unroll
    for (int j = 0; j < 4; ++j)
      bfr[j] = *(const bf16x8*)(Bb + (wc * 64 + j * 16 + l15) * 32 + ((quad ^ fsw) * 8));
    __builtin_amdgcn_s_setprio(1);
#pragma unroll
    for (int i = 0; i < 4; ++i)
#pragma unroll
      for (int j = 0; j < 4; ++j)
        acc[i][j] = __builtin_amdgcn_mfma_f32_16x16x32_bf16(af[i], bfr[j], acc[i][j], 0, 0, 0);
    __builtin_amdgcn_s_setprio(0);
  };

  // 16 K-iterations, 3 LDS buffers, counted vmcnt, one raw barrier per iteration.
  stage(0);
  stage(1);
  int sb = 2, cb = 0;
#pragma unroll 1
  for (int it = 0; it < 14; ++it) {
    asm volatile("s_waitcnt vmcnt(4)" ::: "memory");  // own stage(it) landed; stage(it+1) flies
    asm volatile("s_barrier" ::: "memory");           // all waves: buf(it) ready, buf(sb) free
    stage(sb); sb = (sb == 2) ? 0 : sb + 1;
    compute(cb); cb = (cb == 2) ? 0 : cb + 1;
  }
  asm volatile("s_waitcnt vmcnt(4)" ::: "memory");
  asm volatile("s_barrier" ::: "memory");
  compute(cb); cb = (cb == 2) ? 0 : cb + 1;
  asm volatile("s_waitcnt vmcnt(0)" ::: "memory");
  asm volatile("s_barrier" ::: "memory");
  compute(cb);

#pragma unroll
  for (int i = 0; i < 4; ++i) {
#pragma unroll
    for (int rg = 0; rg < 4; ++rg) {
      int m = mtile * 128 + wr * 64 + i * 16 + quad * 4 + rg;
      if (MODE == 0) {
        int bw = m / Nn, n = m - bw * Nn;
#pragma unroll
        for (int j = 0; j < 4; ++j) {
          int jg = ntile * 128 + wc * 64 + j * 16 + l15;
          float v = acc[i][j][rg] + bias[jg];
          int which = jg >> 9;
          if (which == 0) v *= SCALE;   // fold softmax scale into q
          int h = (jg >> 5) & 15;
          int d = jg & 31;
          long idx = (((long)bw * NHd + h) * Nn + n) * HD + d;
          bf16_t* dst = (which == 0) ? oq : ((which == 1) ? okk : ov);
          dst[idx] = (bf16_t)v;
        }
      } else {
        long pb = (long)token_to_pixel(m) * Cc;
#pragma unroll
        for (int j = 0; j < 4; ++j) {
          int jg = ntile * 128 + wc * 64 + j * 16 + l15;
          of[pb + jg] = acc[i][j][rg] + bias[jg];
        }
      }
    }
  }
}

// Precompute bm[class][h][n][m] = rel-pos bias + shift mask, bf16, [64][64] padded
// with -1e30 for n>=49 or m>=49 (=> exp -> 0, so MFMA padding lanes self-mask).
__global__ void bm_fill(const float* __restrict__ table, bf16_t* __restrict__ bm) {
  const int b = blockIdx.x;           // cls*16 + h
  const int cls = b >> 4, h = b & 15;
  const int whE = cls >> 1, wwE = cls & 1;
  for (int e = threadIdx.x; e < 4096; e += 256) {
    int n = e >> 6, m = e & 63;
    float v = -1e30f;
    if (n < Nn && m < Nn) {
      int r1 = n / 7, c1 = n - r1 * 7;
      int r2 = m / 7, c2 = m - r2 * 7;
      int idx = (r1 - r2 + 6) * 13 + (c1 - c2 + 6);
      v = table[idx * NHd + h];
      int reg1 = (whE ? ((r1 < 4) ? 1 : 2) : 0) * 3 + (wwE ? ((c1 < 4) ? 1 : 2) : 0);
      int reg2 = (whE ? ((r2 < 4) ? 1 : 2) : 0) * 3 + (wwE ? ((c2 < 4) ? 1 : 2) : 0);
      if (reg1 != reg2) v -= 100.f;
    }
    bm[(long)b * 4096 + e] = (bf16_t)v;
  }
}

// MFMA attention. One block per (window, head-quad): bw = blockIdx>>2, each wave
// owns ONE head -> no serial head loop; 8192 blocks x 4 waves = 4x the TLP to hide
// the dependent global-load latency at each head start. No __syncthreads (all LDS
// per-wave). pbuf half-sized [32][72], P double-pumped. LDS 36.9KB -> 4 blocks/CU.
__global__ __launch_bounds__(256, 4)
void attn_k(bf16_t* __restrict__ qr, const bf16_t* __restrict__ kr,
            const bf16_t* __restrict__ vr, const bf16_t* __restrict__ bm) {
  __shared__ __align__(16) bf16_t vt[4][32 * 72];   // V^T per wave: [d][m], stride 72
  __shared__ __align__(16) bf16_t pbuf[4][32 * 72]; // P half-tile per wave: [n%32][m]
  const int t = threadIdx.x, wave = t >> 6, lane = t & 63;
  const int quad = lane >> 4, l15 = lane & 15;
  const int bw = blockIdx.x >> 2;
  const int h = (blockIdx.x & 3) * 4 + wave;
  const int w6 = bw & 63, wh = w6 >> 3, ww = w6 & 7;
  const int cls = ((wh == 7) ? 2 : 0) | ((ww == 7) ? 1 : 0);
  bf16_t* vtw = vt[wave];
  bf16_t* pw  = pbuf[wave];

  // zero vt: cols 50..63 stay zero (m-padding for PV), avoids NaN garbage
  {
    bf16x8 z = {};
    for (int c = lane; c < 288; c += 64) *(bf16x8*)(vtw + c * 8) = z;
  }

  const int dc = lane & 3;        // d-chunk of 8 for V transpose staging
  const int mp = lane >> 2;       // m-pair index
  const int m2 = 32 + 2 * mp;
  const int ma = (m2 > 48) ? 48 : m2;
  const int mb = (m2 + 1 > 48) ? 48 : m2 + 1;

  const long base = (long)(bw * NHd + h) * (Nn * HD);
  const bf16_t* K = kr + base;
  const bf16_t* Q = qr + base;
  const bf16_t* V = vr + base;

  // K/Q fragments straight from global: 16 consecutive rows x 64B = coalesced 1KB/instr.
  // Rows 49..63 over-read into the next head slab: finite garbage, masked by bm pad.
  bf16x8 kf[4], qf[4];
#pragma unroll
  for (int i = 0; i < 4; ++i) {
    kf[i] = *(const bf16x8*)(K + (i * 16 + l15) * HD + quad * 8);
    qf[i] = *(const bf16x8*)(Q + (i * 16 + l15) * HD + quad * 8);
  }
  // V staging loads (issued early; LDS transpose-writes happen after the MFMAs)
  bf16x8 v0a = *(const bf16x8*)(V + (2 * mp) * HD + dc * 8);
  bf16x8 v0b = *(const bf16x8*)(V + (2 * mp + 1) * HD + dc * 8);
  bf16x8 v1a = *(const bf16x8*)(V + ma * HD + dc * 8);
  bf16x8 v1b = *(const bf16x8*)(V + mb * HD + dc * 8);

  // S^T[m][n] = sum_d K[m][d] * Qs[n][d]
  f32x4 acc[4][4];
#pragma unroll
  for (int i = 0; i < 4; ++i)
#pragma unroll
    for (int j = 0; j < 4; ++j) {
      f32x4 z = {};
      acc[i][j] = z;
    }
#pragma unroll
  for (int i = 0; i < 4; ++i)
#pragma unroll
    for (int j = 0; j < 4; ++j)
      acc[i][j] = __builtin_amdgcn_mfma_f32_16x16x32_bf16(kf[i], qf[j], acc[i][j], 0, 0, 0);

  // V^T into LDS: vt[d][m], packed bf16x2 writes (pairs of m)
#pragma unroll
  for (int e = 0; e < 8; ++e) {
    int d = dc * 8 + e;
    bf16x2 w0; w0[0] = v0a[e]; w0[1] = v0b[e];
    *(bf16x2*)(vtw + d * 72 + 2 * mp) = w0;
    if (mp <= 8) {
      bf16x2 w1; w1[0] = v1a[e]; w1[1] = (mp < 8) ? v1b[e] : (bf16_t)0.0f;
      *(bf16x2*)(vtw + d * 72 + ma) = w1;
    }
  }

  // bias+mask+pad, exp, row-sums
  const bf16_t* bmh = bm + ((long)(cls * NHd + h) << 12);
  float psum[4] = {0.f, 0.f, 0.f, 0.f};
#pragma unroll
  for (int j = 0; j < 4; ++j) {
    const int n = j * 16 + l15;
#pragma unroll
    for (int i = 0; i < 4; ++i) {
      bf16x4 bmv = *(const bf16x4*)(bmh + n * 64 + i * 16 + quad * 4);
      f32x4 e;
#pragma unroll
      for (int rg = 0; rg < 4; ++rg)
        e[rg] = __expf(acc[i][j][rg] + (float)bmv[rg]);
      acc[i][j] = e;
      psum[j] += e[0] + e[1] + e[2] + e[3];
    }
  }
  float inv[4];
#pragma unroll
  for (int j = 0; j < 4; ++j) {
    float s = psum[j];
    s += __shfl_xor(s, 16);
    s += __shfl_xor(s, 32);
    inv[j] = (s > 0.f) ? (1.f / s) : 0.f;   // padded queries: sum==0 -> P=0, no NaN
  }

  // hoist V fragments (vt writes above are same-wave ordered before these reads)
  bf16x8 vf[2][2];
#pragma unroll
  for (int mk = 0; mk < 2; ++mk)
#pragma unroll
    for (int dt = 0; dt < 2; ++dt)
      vf[mk][dt] = *(const bf16x8*)(vtw + (dt * 16 + l15) * 72 + mk * 32 + quad * 8);

  // O^T[d][n] = sum_m VT[d][m] * P[n][m], double-pumped through half-size pbuf
  f32x4 acc2[2][4];
#pragma unroll
  for (int dt = 0; dt < 2; ++dt)
#pragma unroll
    for (int nt = 0; nt < 4; ++nt) {
      f32x4 z = {};
      acc2[dt][nt] = z;
    }
#pragma unroll
  for (int jh = 0; jh < 2; ++jh) {
#pragma unroll
    for (int jl = 0; jl < 2; ++jl) {
      const int j = jh * 2 + jl;
#pragma unroll
      for (int i = 0; i < 4; ++i) {
        bf16x4 pv;
#pragma unroll
        for (int rg = 0; rg < 4; ++rg) pv[rg] = (bf16_t)(acc[i][j][rg] * inv[j]);
        *(bf16x4*)(pw + (jl * 16 + l15) * 72 + i * 16 + quad * 4) = pv;
      }
    }
#pragma unroll
    for (int mk = 0; mk < 2; ++mk) {
      bf16x8 pf[2];
#pragma unroll
      for (int jl = 0; jl < 2; ++jl)
        pf[jl] = *(const bf16x8*)(pw + (jl * 16 + l15) * 72 + mk * 32 + quad * 8);
#pragma unroll
      for (int dt = 0; dt < 2; ++dt)
#pragma unroll
        for (int jl = 0; jl < 2; ++jl)
          acc2[dt][jh * 2 + jl] =
              __builtin_amdgcn_mfma_f32_16x16x32_bf16(vf[mk][dt], pf[jl], acc2[dt][jh * 2 + jl], 0, 0, 0);
    }
  }

  // store O[n][d] back over the q slab (this head's Q already consumed)
  bf16_t* O = qr + base;
#pragma unroll
  for (int nt = 0; nt < 4; ++nt) {
    int n = nt * 16 + l15;
    if (n < Nn) {
#pragma unroll
      for (int dt = 0; dt < 2; ++dt) {
        bf16x4 ov;
#pragma unroll
        for (int rg = 0; rg < 4; ++rg) ov[rg] = (bf16_t)acc2[dt][nt][rg];
        *(bf16x4*)(O + n * HD + dt * 16 + quad * 4) = ov;
      }
    }
  }
}

extern "C" void kernel_launch(void* const* d_in, const int* in_sizes, int n_in,
                              void* d_out, int out_size, void* d_ws, size_t ws_size,
                              hipStream_t stream) {
  const float* x      = (const float*)d_in[0];
  const float* qkv_w  = (const float*)d_in[1];
  const float* qkv_b  = (const float*)d_in[2];
  const float* proj_w = (const float*)d_in[3];
  const float* proj_b = (const float*)d_in[4];
  const float* table  = (const float*)d_in[5];
  float* out = (float*)d_out;

  bf16_t* qr = (bf16_t*)d_ws;                 // q, later overwritten with attn_out
  bf16_t* kr = qr + Mtot * Cc;
  bf16_t* vr = kr + Mtot * Cc;

  // d_out doubles as scratch for everything consumed before gemm_k<1> runs:
  //   xb  @ 0        : 102,760,448 B (bf16 gathered x)
  //   bm  @ 102.76MB :     524,288 B (bias+mask table)
  //   qwb @ +512KB   :   1,572,864 B (bf16 qkv weights)
  char* ob = (char*)d_out;
  bf16_t* xb  = (bf16_t*)ob;
  bf16_t* bmb = (bf16_t*)(ob + 102760448);
  bf16_t* qwb = (bf16_t*)(ob + 102760448 + 524288);
  bf16_t* pwb = kr;   // proj_w bf16 into kr (dead after attn_k)

  prep_k<<<dim3(Mtot / 4 + 384), dim3(256), 0, stream>>>(x, qkv_w, xb, qwb);
  bm_fill<<<dim3(64), dim3(256), 0, stream>>>(table, bmb);
  dim3 g1(12, 784);   // ntile fast; XCD-chunked swizzle inside the kernel
  gemm_k<0><<<g1, 256, 0, stream>>>(xb, qwb, qkv_b, qr, kr, vr, nullptr);
  attn_k<<<dim3(8192), dim3(256), 0, stream>>>(qr, kr, vr, bmb);
  convp_k<<<dim3(128), dim3(256), 0, stream>>>(proj_w, pwb);
  dim3 g3(4, 784);
  gemm_k<1><<<g3, 256, 0, stream>>>(qr, pwb, proj_b, nullptr, nullptr, nullptr, out);
}

// Round 6
// 798.967 us; speedup vs baseline: 1.0411x; 1.0204x over previous
//
#include <hip/hip_runtime.h>
#include <hip/hip_bf16.h>

typedef __bf16 bf16_t;
typedef __bf16 bf16x8 __attribute__((ext_vector_type(8)));
typedef __bf16 bf16x4 __attribute__((ext_vector_type(4)));
typedef __bf16 bf16x2 __attribute__((ext_vector_type(2)));
typedef float f32x4 __attribute__((ext_vector_type(4)));

typedef const __attribute__((address_space(1))) void* gas_t;
typedef __attribute__((address_space(3))) void* las_t;

constexpr int Hh = 56;
constexpr int Ww = 56;
constexpr int Cc = 512;
constexpr int NHd = 16;
constexpr int HD = 32;
constexpr int SSh = 3;
constexpr int Nn = 49;          // tokens per window
constexpr long Mtot = 100352;   // 32*64*49 windowed tokens
#define SCALE 0.17677669529663687f

// token (windowed order) -> pixel index in x / out. Identical map for gather and scatter.
__device__ __forceinline__ int token_to_pixel(int m) {
  int bw = m / Nn;
  int n  = m - bw * Nn;
  int b  = bw >> 6;
  int w6 = bw & 63;
  int wh = w6 >> 3, ww = w6 & 7;
  int r = n / 7, c = n - r * 7;
  int hh = wh * 7 + r + SSh; if (hh >= Hh) hh -= Hh;
  int wp = ww * 7 + c + SSh; if (wp >= Ww) wp -= Ww;
  return (b * Hh + hh) * Ww + wp;
}

// qkv_w f32 -> bf16 (3MB, ~2us)
__global__ __launch_bounds__(256)
void wconv_k(const float* __restrict__ w, bf16_t* __restrict__ wb) {
  const long off = (long)blockIdx.x * 2048 + threadIdx.x * 8;
  f32x4 a0 = *(const f32x4*)(w + off);
  f32x4 a1 = *(const f32x4*)(w + off + 4);
  bf16x8 o;
#pragma unroll
  for (int e = 0; e < 4; ++e) { o[e] = (bf16_t)a0[e]; o[e + 4] = (bf16_t)a1[e]; }
  *(bf16x8*)(wb + off) = o;
}

// Precompute bm[class][h][n][m] = rel-pos bias + shift mask, bf16, [64][64] padded
// with -1e30 for n>=49 or m>=49 (=> exp -> 0, so MFMA padding lanes self-mask).
__global__ void bm_fill(const float* __restrict__ table, bf16_t* __restrict__ bm) {
  const int b = blockIdx.x;           // cls*16 + h
  const int cls = b >> 4, h = b & 15;
  const int whE = cls >> 1, wwE = cls & 1;
  for (int e = threadIdx.x; e < 4096; e += 256) {
    int n = e >> 6, m = e & 63;
    float v = -1e30f;
    if (n < Nn && m < Nn) {
      int r1 = n / 7, c1 = n - r1 * 7;
      int r2 = m / 7, c2 = m - r2 * 7;
      int idx = (r1 - r2 + 6) * 13 + (c1 - c2 + 6);
      v = table[idx * NHd + h];
      int reg1 = (whE ? ((r1 < 4) ? 1 : 2) : 0) * 3 + (wwE ? ((c1 < 4) ? 1 : 2) : 0);
      int reg2 = (whE ? ((r2 < 4) ? 1 : 2) : 0) * 3 + (wwE ? ((c2 < 4) ? 1 : 2) : 0);
      if (reg1 != reg2) v -= 100.f;
    }
    bm[(long)b * 4096 + e] = (bf16_t)v;
  }
}

// QKV GEMM, prep fused. C[m][n] = sum_k x[tok(m)][k]*Wb[n][k] (+bias).
// A: f32 gathered rows -> regs -> cvt -> ds_write into swizzled DOUBLE-buffered LDS.
// B: bf16 weights via global_load_lds (inverse-swizzled source) into TRIPLE buffer.
// Counted vmcnt (T4): vmcnt(2)=own A regs ready; vmcnt(6)=B(t) landed with
// A(t+1)+B(t+1) still in flight across the raw s_barrier. One barrier/iter.
// Swizzle: slot(r,s) holds chunk s^((r>>1)&3) (verified conflict-free in r5).
// XCD-chunked tile order (T1): 12 ntile-siblings of an mtile on one XCD -> A L2-hit.
__global__ __launch_bounds__(256, 3)
void qkv_gemm_k(const float* __restrict__ X, const bf16_t* __restrict__ Wb,
                const float* __restrict__ bias,
                bf16_t* __restrict__ oq, bf16_t* __restrict__ okk, bf16_t* __restrict__ ov) {
  __shared__ __align__(16) bf16_t lA[2 * 128 * 32];
  __shared__ __align__(16) bf16_t lB[3 * 128 * 32];
  const int t = threadIdx.x;
  const int hflat = blockIdx.y * 12 + blockIdx.x;
  const int l = (hflat & 7) * 1176 + (hflat >> 3);   // XCD-chunked, bijective
  const int mtile = l / 12, ntile = l % 12;
  const int lane = t & 63;
  const int wave = t >> 6;
  const int wr = wave >> 1, wc = wave & 1;
  const int quad = lane >> 4, l15 = lane & 15;

  // A staging (regs): thread covers rows r0, r0+64; logical chunk cA (8 f32 = 32B).
  const int r0 = t >> 2, cA = t & 3;
  const int sA = cA ^ ((r0 >> 1) & 3);               // (r0+64)>>1 keeps &3 ==> same slot
  const float* aRow[2];
  bf16_t* aDst[2];
#pragma unroll
  for (int p = 0; p < 2; ++p) {
    aRow[p] = X + (long)token_to_pixel(mtile * 128 + r0 + p * 64) * Cc + cA * 8;
    aDst[p] = lA + (r0 + p * 64) * 32 + sA * 8;
  }
  // B staging (gload): source pre-swizzled, linear LDS dest (wave base + lane*16)
  const int csw = (t & 3) ^ ((t >> 3) & 3);
  const bf16_t* bSrc[2];
#pragma unroll
  for (int p = 0; p < 2; ++p)
    bSrc[p] = Wb + (long)(ntile * 128 + (t >> 2) + p * 64) * Cc + csw * 8;
  char* lBw = (char*)lB + wave * 1024;

  const int fsw = (l15 >> 1) & 3;
  f32x4 acc[4][4] = {};
  f32x4 aR[2][2];

  auto issueA = [&](int it) {
#pragma unroll
    for (int p = 0; p < 2; ++p) {
      aR[p][0] = *(const f32x4*)(aRow[p] + it * 32);
      aR[p][1] = *(const f32x4*)(aRow[p] + it * 32 + 4);
    }
  };
  auto issueB = [&](int it, int gb) {
#pragma unroll
    for (int p = 0; p < 2; ++p)
      __builtin_amdgcn_global_load_lds((gas_t)(bSrc[p] + it * 32),
                                       (las_t)(lBw + gb * 8192 + p * 4096), 16, 0, 0);
  };
  auto writeA = [&](int ab) {
#pragma unroll
    for (int p = 0; p < 2; ++p) {
      bf16x8 o;
#pragma unroll
      for (int e = 0; e < 4; ++e) { o[e] = (bf16_t)aR[p][0][e]; o[e + 4] = (bf16_t)aR[p][1][e]; }
      *(bf16x8*)(aDst[p] + ab * 4096) = o;
    }
  };
  auto compute = [&](int ab, int gb) {
    const bf16_t* Ab = lA + ab * 4096;
    const bf16_t* Bb = lB + gb * 4096;
    bf16x8 af[4], bfr[4];
#pragma unroll
    for (int i = 0; i < 4; ++i)
      af[i] = *(const bf16x8*)(Ab + (wr * 64 + i * 16 + l15) * 32 + ((quad ^ fsw) * 8));
#pragma unroll
    for (int j = 0; j < 4; ++j)
      bfr[j] = *(const bf16x8*)(Bb + (wc * 64 + j * 16 + l15) * 32 + ((quad ^ fsw) * 8));
    __builtin_amdgcn_s_setprio(1);
#pragma unroll
    for (int i = 0; i < 4; ++i)
#pragma unroll
      for (int j = 0; j < 4; ++j)
        acc[i][j] = __builtin_amdgcn_mfma_f32_16x16x32_bf16(af[i], bfr[j], acc[i][j], 0, 0, 0);
    __builtin_amdgcn_s_setprio(0);
  };

  issueA(0);
  issueB(0, 0);
  int ab = 0, gb = 0, gbn = 1;
#pragma unroll 1
  for (int it = 0; it < 16; ++it) {
    asm volatile("s_waitcnt vmcnt(2)" ::: "memory");   // A(it) regs ready; B(it) may fly
    writeA(ab);
    if (it < 15) {
      issueA(it + 1);
      issueB(it + 1, gbn);
      asm volatile("s_waitcnt vmcnt(6)" ::: "memory"); // B(it) landed; 6 newer in flight
    } else {
      asm volatile("s_waitcnt vmcnt(0)" ::: "memory");
    }
    asm volatile("s_waitcnt lgkmcnt(0)" ::: "memory"); // my A ds_writes done
    asm volatile("s_barrier" ::: "memory");            // tile(it) visible to all waves
    compute(ab, gb);
    ab ^= 1;
    gb = gbn; gbn = (gbn == 2) ? 0 : gbn + 1;
  }

#pragma unroll
  for (int i = 0; i < 4; ++i) {
#pragma unroll
    for (int rg = 0; rg < 4; ++rg) {
      int m = mtile * 128 + wr * 64 + i * 16 + quad * 4 + rg;
      int bw = m / Nn, n = m - bw * Nn;
#pragma unroll
      for (int j = 0; j < 4; ++j) {
        int jg = ntile * 128 + wc * 64 + j * 16 + l15;
        float v = acc[i][j][rg] + bias[jg];
        int which = jg >> 9;
        if (which == 0) v *= SCALE;   // fold softmax scale into q
        int h = (jg >> 5) & 15;
        int d = jg & 31;
        long idx = (((long)bw * NHd + h) * Nn + n) * HD + d;
        bf16_t* dst = (which == 0) ? oq : ((which == 1) ? okk : ov);
        dst[idx] = (bf16_t)v;
      }
    }
  }
}

// Proj GEMM, weight-convert fused. A = attn_out (bw,h,n,d) bf16 via global_load_lds
// (triple buffer, source-swizzled); B = proj_w f32 via regs->cvt->ds_write (double
// buffer). Same counted-vmcnt 1-barrier pipeline as qkv_gemm_k, roles swapped.
__global__ __launch_bounds__(256, 3)
void proj_gemm_k(const bf16_t* __restrict__ Aq, const float* __restrict__ Wf,
                 const float* __restrict__ bias, float* __restrict__ of) {
  __shared__ __align__(16) bf16_t lA[3 * 128 * 32];   // gload side
  __shared__ __align__(16) bf16_t lB[2 * 128 * 32];   // reg side
  const int t = threadIdx.x;
  const int hflat = blockIdx.y * 4 + blockIdx.x;
  const int l = (hflat & 7) * 392 + (hflat >> 3);
  const int mtile = l / 4, ntile = l % 4;
  const int lane = t & 63;
  const int wave = t >> 6;
  const int wr = wave >> 1, wc = wave & 1;
  const int quad = lane >> 4, l15 = lane & 15;

  // B staging (regs, f32 proj_w rows)
  const int r0 = t >> 2, cB = t & 3;
  const int sB = cB ^ ((r0 >> 1) & 3);
  const float* bRow[2];
  bf16_t* bDst[2];
#pragma unroll
  for (int p = 0; p < 2; ++p) {
    bRow[p] = Wf + (long)(ntile * 128 + r0 + p * 64) * Cc + cB * 8;
    bDst[p] = lB + (r0 + p * 64) * 32 + sB * 8;
  }
  // A staging (gload, head-major layout): k = it*32 + csw*8 + e -> head=it, d=csw*8+e
  const int csw = (t & 3) ^ ((t >> 3) & 3);
  const bf16_t* aSrc[2];
#pragma unroll
  for (int p = 0; p < 2; ++p) {
    int m = mtile * 128 + (t >> 2) + p * 64;
    int bw2 = m / Nn, nn = m - bw2 * Nn;
    aSrc[p] = Aq + (long)bw2 * (NHd * Nn * HD) + nn * HD + csw * 8;
  }
  char* lAw = (char*)lA + wave * 1024;

  const int fsw = (l15 >> 1) & 3;
  f32x4 acc[4][4] = {};
  f32x4 bR[2][2];

  auto issueB = [&](int it) {
#pragma unroll
    for (int p = 0; p < 2; ++p) {
      bR[p][0] = *(const f32x4*)(bRow[p] + it * 32);
      bR[p][1] = *(const f32x4*)(bRow[p] + it * 32 + 4);
    }
  };
  auto issueA = [&](int it, int gb) {
#pragma unroll
    for (int p = 0; p < 2; ++p)
      __builtin_amdgcn_global_load_lds((gas_t)(aSrc[p] + (long)it * (Nn * HD)),
                                       (las_t)(lAw + gb * 8192 + p * 4096), 16, 0, 0);
  };
  auto writeB = [&](int ab) {
#pragma unroll
    for (int p = 0; p < 2; ++p) {
      bf16x8 o;
#pragma unroll
      for (int e = 0; e < 4; ++e) { o[e] = (bf16_t)bR[p][0][e]; o[e + 4] = (bf16_t)bR[p][1][e]; }
      *(bf16x8*)(bDst[p] + ab * 4096) = o;
    }
  };
  auto compute = [&](int ab, int gb) {
    const bf16_t* Ab = lA + gb * 4096;
    const bf16_t* Bb = lB + ab * 4096;
    bf16x8 af[4], bfr[4];
#pragma unroll
    for (int i = 0; i < 4; ++i)
      af[i] = *(const bf16x8*)(Ab + (wr * 64 + i * 16 + l15) * 32 + ((quad ^ fsw) * 8));
#pragma unroll
    for (int j = 0; j < 4; ++j)
      bfr[j] = *(const bf16x8*)(Bb + (wc * 64 + j * 16 + l15) * 32 + ((quad ^ fsw) * 8));
    __builtin_amdgcn_s_setprio(1);
#pragma unroll
    for (int i = 0; i < 4; ++i)
#pragma unroll
      for (int j = 0; j < 4; ++j)
        acc[i][j] = __builtin_amdgcn_mfma_f32_16x16x32_bf16(af[i], bfr[j], acc[i][j], 0, 0, 0);
    __builtin_amdgcn_s_setprio(0);
  };

  issueB(0);
  issueA(0, 0);
  int ab = 0, gb = 0, gbn = 1;
#pragma unroll 1
  for (int it = 0; it < 16; ++it) {
    asm volatile("s_waitcnt vmcnt(2)" ::: "memory");
    writeB(ab);
    if (it < 15) {
      issueB(it + 1);
      issueA(it + 1, gbn);
      asm volatile("s_waitcnt vmcnt(6)" ::: "memory");
    } else {
      asm volatile("s_waitcnt vmcnt(0)" ::: "memory");
    }
    asm volatile("s_waitcnt lgkmcnt(0)" ::: "memory");
    asm volatile("s_barrier" ::: "memory");
    compute(ab, gb);
    ab ^= 1;
    gb = gbn; gbn = (gbn == 2) ? 0 : gbn + 1;
  }

#pragma unroll
  for (int i = 0; i < 4; ++i) {
#pragma unroll
    for (int rg = 0; rg < 4; ++rg) {
      int m = mtile * 128 + wr * 64 + i * 16 + quad * 4 + rg;
      long pb = (long)token_to_pixel(m) * Cc;
#pragma unroll
      for (int j = 0; j < 4; ++j) {
        int jg = ntile * 128 + wc * 64 + j * 16 + l15;
        of[pb + jg] = acc[i][j][rg] + bias[jg];
      }
    }
  }
}

// MFMA attention. One block per (window, head-quad); each wave owns ONE head.
// No __syncthreads (all LDS per-wave). pbuf half-sized [32][72], P double-pumped.
// LDS 36.9KB -> 4 blocks/CU. T5 setprio around both MFMA clusters.
__global__ __launch_bounds__(256, 4)
void attn_k(bf16_t* __restrict__ qr, const bf16_t* __restrict__ kr,
            const bf16_t* __restrict__ vr, const bf16_t* __restrict__ bm) {
  __shared__ __align__(16) bf16_t vt[4][32 * 72];   // V^T per wave: [d][m], stride 72
  __shared__ __align__(16) bf16_t pbuf[4][32 * 72]; // P half-tile per wave: [n%32][m]
  const int t = threadIdx.x, wave = t >> 6, lane = t & 63;
  const int quad = lane >> 4, l15 = lane & 15;
  const int bw = blockIdx.x >> 2;
  const int h = (blockIdx.x & 3) * 4 + wave;
  const int w6 = bw & 63, wh = w6 >> 3, ww = w6 & 7;
  const int cls = ((wh == 7) ? 2 : 0) | ((ww == 7) ? 1 : 0);
  bf16_t* vtw = vt[wave];
  bf16_t* pw  = pbuf[wave];

  // zero vt: cols 50..63 stay zero (m-padding for PV), avoids NaN garbage
  {
    bf16x8 z = {};
    for (int c = lane; c < 288; c += 64) *(bf16x8*)(vtw + c * 8) = z;
  }

  const int dc = lane & 3;        // d-chunk of 8 for V transpose staging
  const int mp = lane >> 2;       // m-pair index
  const int m2 = 32 + 2 * mp;
  const int ma = (m2 > 48) ? 48 : m2;
  const int mb = (m2 + 1 > 48) ? 48 : m2 + 1;

  const long base = (long)(bw * NHd + h) * (Nn * HD);
  const bf16_t* K = kr + base;
  const bf16_t* Q = qr + base;
  const bf16_t* V = vr + base;

  // K/Q fragments straight from global: 16 consecutive rows x 64B = coalesced 1KB/instr.
  // Rows 49..63 over-read into the next head slab: finite garbage, masked by bm pad.
  bf16x8 kf[4], qf[4];
#pragma unroll
  for (int i = 0; i < 4; ++i) {
    kf[i] = *(const bf16x8*)(K + (i * 16 + l15) * HD + quad * 8);
    qf[i] = *(const bf16x8*)(Q + (i * 16 + l15) * HD + quad * 8);
  }
  // V staging loads (issued early; LDS transpose-writes happen after the MFMAs)
  bf16x8 v0a = *(const bf16x8*)(V + (2 * mp) * HD + dc * 8);
  bf16x8 v0b = *(const bf16x8*)(V + (2 * mp + 1) * HD + dc * 8);
  bf16x8 v1a = *(const bf16x8*)(V + ma * HD + dc * 8);
  bf16x8 v1b = *(const bf16x8*)(V + mb * HD + dc * 8);

  // S^T[m][n] = sum_d K[m][d] * Qs[n][d]
  f32x4 acc[4][4];
#pragma unroll
  for (int i = 0; i < 4; ++i)
#pragma unroll
    for (int j = 0; j < 4; ++j) {
      f32x4 z = {};
      acc[i][j] = z;
    }
  __builtin_amdgcn_s_setprio(1);
#pragma unroll
  for (int i = 0; i < 4; ++i)
#pragma unroll
    for (int j = 0; j < 4; ++j)
      acc[i][j] = __builtin_amdgcn_mfma_f32_16x16x32_bf16(kf[i], qf[j], acc[i][j], 0, 0, 0);
  __builtin_amdgcn_s_setprio(0);

  // V^T into LDS: vt[d][m], packed bf16x2 writes (pairs of m)
#pragma unroll
  for (int e = 0; e < 8; ++e) {
    int d = dc * 8 + e;
    bf16x2 w0; w0[0] = v0a[e]; w0[1] = v0b[e];
    *(bf16x2*)(vtw + d * 72 + 2 * mp) = w0;
    if (mp <= 8) {
      bf16x2 w1; w1[0] = v1a[e]; w1[1] = (mp < 8) ? v1b[e] : (bf16_t)0.0f;
      *(bf16x2*)(vtw + d * 72 + ma) = w1;
    }
  }

  // bias+mask+pad, exp, row-sums
  const bf16_t* bmh = bm + ((long)(cls * NHd + h) << 12);
  float psum[4] = {0.f, 0.f, 0.f, 0.f};
#pragma unroll
  for (int j = 0; j < 4; ++j) {
    const int n = j * 16 + l15;
#pragma unroll
    for (int i = 0; i < 4; ++i) {
      bf16x4 bmv = *(const bf16x4*)(bmh + n * 64 + i * 16 + quad * 4);
      f32x4 e;
#pragma unroll
      for (int rg = 0; rg < 4; ++rg)
        e[rg] = __expf(acc[i][j][rg] + (float)bmv[rg]);
      acc[i][j] = e;
      psum[j] += e[0] + e[1] + e[2] + e[3];
    }
  }
  float inv[4];
#pragma unroll
  for (int j = 0; j < 4; ++j) {
    float s = psum[j];
    s += __shfl_xor(s, 16);
    s += __shfl_xor(s, 32);
    inv[j] = (s > 0.f) ? (1.f / s) : 0.f;   // padded queries: sum==0 -> P=0, no NaN
  }

  // hoist V fragments (vt writes above are same-wave ordered before these reads)
  bf16x8 vf[2][2];
#pragma unroll
  for (int mk = 0; mk < 2; ++mk)
#pragma unroll
    for (int dt = 0; dt < 2; ++dt)
      vf[mk][dt] = *(const bf16x8*)(vtw + (dt * 16 + l15) * 72 + mk * 32 + quad * 8);

  // O^T[d][n] = sum_m VT[d][m] * P[n][m], double-pumped through half-size pbuf
  f32x4 acc2[2][4];
#pragma unroll
  for (int dt = 0; dt < 2; ++dt)
#pragma unroll
    for (int nt = 0; nt < 4; ++nt) {
      f32x4 z = {};
      acc2[dt][nt] = z;
    }
#pragma unroll
  for (int jh = 0; jh < 2; ++jh) {
#pragma unroll
    for (int jl = 0; jl < 2; ++jl) {
      const int j = jh * 2 + jl;
#pragma unroll
      for (int i = 0; i < 4; ++i) {
        bf16x4 pv;
#pragma unroll
        for (int rg = 0; rg < 4; ++rg) pv[rg] = (bf16_t)(acc[i][j][rg] * inv[j]);
        *(bf16x4*)(pw + (jl * 16 + l15) * 72 + i * 16 + quad * 4) = pv;
      }
    }
    __builtin_amdgcn_s_setprio(1);
#pragma unroll
    for (int mk = 0; mk < 2; ++mk) {
      bf16x8 pf[2];
#pragma unroll
      for (int jl = 0; jl < 2; ++jl)
        pf[jl] = *(const bf16x8*)(pw + (jl * 16 + l15) * 72 + mk * 32 + quad * 8);
#pragma unroll
      for (int dt = 0; dt < 2; ++dt)
#pragma unroll
        for (int jl = 0; jl < 2; ++jl)
          acc2[dt][jh * 2 + jl] =
              __builtin_amdgcn_mfma_f32_16x16x32_bf16(vf[mk][dt], pf[jl], acc2[dt][jh * 2 + jl], 0, 0, 0);
    }
    __builtin_amdgcn_s_setprio(0);
  }

  // store O[n][d] back over the q slab (this head's Q already consumed)
  bf16_t* O = qr + base;
#pragma unroll
  for (int nt = 0; nt < 4; ++nt) {
    int n = nt * 16 + l15;
    if (n < Nn) {
#pragma unroll
      for (int dt = 0; dt < 2; ++dt) {
        bf16x4 ov;
#pragma unroll
        for (int rg = 0; rg < 4; ++rg) ov[rg] = (bf16_t)acc2[dt][nt][rg];
        *(bf16x4*)(O + n * HD + dt * 16 + quad * 4) = ov;
      }
    }
  }
}

extern "C" void kernel_launch(void* const* d_in, const int* in_sizes, int n_in,
                              void* d_out, int out_size, void* d_ws, size_t ws_size,
                              hipStream_t stream) {
  const float* x      = (const float*)d_in[0];
  const float* qkv_w  = (const float*)d_in[1];
  const float* qkv_b  = (const float*)d_in[2];
  const float* proj_w = (const float*)d_in[3];
  const float* proj_b = (const float*)d_in[4];
  const float* table  = (const float*)d_in[5];
  float* out = (float*)d_out;

  bf16_t* qr = (bf16_t*)d_ws;                 // q, later overwritten with attn_out
  bf16_t* kr = qr + Mtot * Cc;
  bf16_t* vr = kr + Mtot * Cc;

  // d_out doubles as scratch consumed before proj_gemm_k runs:
  //   bm  @ 0      :   524,288 B (bias+mask table)
  //   qwb @ 512KB  : 1,572,864 B (bf16 qkv weights)
  char* ob = (char*)d_out;
  bf16_t* bmb = (bf16_t*)ob;
  bf16_t* qwb = (bf16_t*)(ob + 524288);

  bm_fill<<<dim3(64), dim3(256), 0, stream>>>(table, bmb);
  wconv_k<<<dim3(384), dim3(256), 0, stream>>>(qkv_w, qwb);
  dim3 g1(12, 784);
  qkv_gemm_k<<<g1, 256, 0, stream>>>(x, qwb, qkv_b, qr, kr, vr);
  attn_k<<<dim3(8192), dim3(256), 0, stream>>>(qr, kr, vr, bmb);
  dim3 g3(4, 784);
  proj_gemm_k<<<g3, 256, 0, stream>>>(qr, proj_w, proj_b, out);
}